// Round 9
// baseline (810.167 us; speedup 1.0000x reference)
//
#include <hip/hip_runtime.h>
#include <hip/hip_bf16.h>
#include <math.h>

#define N_NODES 50000
#define N_EDGES 800000
#define TOPK 512

__device__ __forceinline__ float lrelu02(float v) { return v > 0.f ? v : 0.2f * v; }

__device__ __forceinline__ unsigned short f2bf(float f) {
    unsigned u = __float_as_uint(f);
    u += 0x7fffu + ((u >> 16) & 1u);       // RNE
    return (unsigned short)(u >> 16);
}

// ---------------- CSR build (counting sort by dst), both graphs ----------------
__global__ void k_count2(const int* __restrict__ ei1, const int* __restrict__ ei2,
                         int* __restrict__ cnt1, int* __restrict__ cnt2) {
    int e = blockIdx.x * 256 + threadIdx.x;
    if (e < N_EDGES) atomicAdd(&cnt1[ei1[N_EDGES + e]], 1);
    else if (e < 2 * N_EDGES) atomicAdd(&cnt2[ei2[e]], 1);  // ei2[E + (e-E)] == ei2[e]
}

__global__ __launch_bounds__(1024) void k_scan1(const int* __restrict__ cnt1, const int* __restrict__ cnt2,
                                                int* __restrict__ rp1, int* __restrict__ rp2,
                                                int* __restrict__ part1, int* __restrict__ part2) {
    __shared__ int lds[1024];
    int g = blockIdx.y;
    const int* cnt = g ? cnt2 : cnt1;
    int* rp = g ? rp2 : rp1;
    int* part = g ? part2 : part1;
    int t = threadIdx.x;
    int i = blockIdx.x * 1024 + t;
    int v = (i < N_NODES) ? cnt[i] : 0;
    lds[t] = v;
    __syncthreads();
    for (int off = 1; off < 1024; off <<= 1) {
        int add = (t >= off) ? lds[t - off] : 0;
        __syncthreads();
        lds[t] += add;
        __syncthreads();
    }
    if (i < N_NODES) rp[i] = lds[t] - v;   // block-local exclusive
    if (t == 1023) part[blockIdx.x] = lds[1023];
}

__global__ __launch_bounds__(128) void k_scan2(const int* __restrict__ part1, const int* __restrict__ part2,
                                               int* __restrict__ bo1, int* __restrict__ bo2,
                                               int* __restrict__ rp1, int* __restrict__ rp2) {
    int t = threadIdx.x, g = t >> 6, lane = t & 63;
    const int* part = g ? part2 : part1;
    int* bo = g ? bo2 : bo1;
    int v = (lane < 49) ? part[lane] : 0;
    int p = v;
    for (int d = 1; d < 64; d <<= 1) { int u = __shfl_up(p, d, 64); if (lane >= d) p += u; }
    if (lane < 49) bo[lane] = p - v;
    if (lane == 0) (g ? rp2 : rp1)[N_NODES] = N_EDGES;
}

__global__ __launch_bounds__(1024) void k_scan3(int* __restrict__ rp1, int* __restrict__ rp2,
                                                const int* __restrict__ bo1, const int* __restrict__ bo2) {
    int g = blockIdx.y;
    int* rp = g ? rp2 : rp1;
    int add = (g ? bo2 : bo1)[blockIdx.x];
    int i = blockIdx.x * 1024 + threadIdx.x;
    if (i < N_NODES) rp[i] += add;
}

__global__ void k_scatter2(const int* __restrict__ ei1, const int* __restrict__ ei2,
                           const int* __restrict__ rp1, const int* __restrict__ rp2,
                           int* __restrict__ cur1, int* __restrict__ cur2,
                           int* __restrict__ ssrc1, int* __restrict__ ssrc2) {
    int e = blockIdx.x * 256 + threadIdx.x;
    if (e < N_EDGES) {
        int src = ei1[e], dst = ei1[N_EDGES + e];
        ssrc1[rp1[dst] + atomicAdd(&cur1[dst], 1)] = src;
    } else if (e < 2 * N_EDGES) {
        int ee = e - N_EDGES;
        int src = ei2[ee], dst = ei2[e];
        ssrc2[rp2[dst] + atomicAdd(&cur2[dst], 1)] = src;
    }
}

// ---------------- GEMM (x @ W) with fused attention logits, bf16 output ----------------
// IN_BF16: input rows are bf16 (layer-2, reads tmp) vs f32 (layer-1).
template<int IN_BF16>
__global__ __launch_bounds__(256) void k_gemm_att(
    const void* __restrict__ XA_, const void* __restrict__ XB_, const float* __restrict__ W,
    const float* __restrict__ a_src, const float* __restrict__ a_dst,
    unsigned short* __restrict__ YA, unsigned short* __restrict__ YB,
    float2* __restrict__ alsA, float2* __restrict__ aldA,
    float2* __restrict__ alsB, float2* __restrict__ aldB) {
    __shared__ __align__(16) float Xs[64][128];
    __shared__ __align__(16) float Wl[128][64];
    int t = threadIdx.x;
    int head = blockIdx.y;
    int row0 = blockIdx.x * 64;
    const void* X = blockIdx.z ? XB_ : XA_;
    unsigned short* Y = blockIdx.z ? YB : YA;
    float* als = (float*)(blockIdx.z ? alsB : alsA);
    float* ald = (float*)(blockIdx.z ? aldB : aldA);

    const float4* W4 = (const float4*)W;
    float4* Wl4 = (float4*)Wl;
    #pragma unroll
    for (int i = 0; i < 8; ++i) {
        int e = i * 256 + t;
        int k = e >> 4, cc = e & 15;
        Wl4[k * 16 + cc] = W4[k * 32 + head * 16 + cc];
    }
    float4* Xs4 = (float4*)Xs;
    if (IN_BF16) {
        const uint4* Xb = (const uint4*)X;     // row = 16 x (8 bf16)
        #pragma unroll
        for (int i = 0; i < 4; ++i) {
            int e = i * 256 + t;               // 0..1023
            int r = e >> 4, c8 = e & 15;
            int g = row0 + r;
            uint4 v = make_uint4(0u, 0u, 0u, 0u);
            if (g < N_NODES) v = Xb[g * 16 + c8];
            float4 f0 = make_float4(__uint_as_float(v.x << 16), __uint_as_float(v.x & 0xffff0000u),
                                    __uint_as_float(v.y << 16), __uint_as_float(v.y & 0xffff0000u));
            float4 f1 = make_float4(__uint_as_float(v.z << 16), __uint_as_float(v.z & 0xffff0000u),
                                    __uint_as_float(v.w << 16), __uint_as_float(v.w & 0xffff0000u));
            int c0 = c8 * 2, c1 = c0 + 1;
            Xs4[r * 32 + ((c0 + r + (r >> 2)) & 31)] = f0;
            Xs4[r * 32 + ((c1 + r + (r >> 2)) & 31)] = f1;
        }
    } else {
        const float4* X4 = (const float4*)X;   // row = 32 float4
        #pragma unroll
        for (int i = 0; i < 8; ++i) {
            int e = i * 256 + t;               // 0..2047
            int r = e >> 5, c = e & 31;
            int g = row0 + r;
            float4 v = make_float4(0.f, 0.f, 0.f, 0.f);
            if (g < N_NODES) v = X4[(size_t)g * 32 + c];
            int ch = (c + r + (r >> 2)) & 31;  // bank-conflict swizzle
            Xs4[r * 32 + ch] = v;
        }
    }
    __syncthreads();

    int tc = t & 15, tr = t >> 4;
    int r0 = tr * 4;
    float acc[4][4];
    #pragma unroll
    for (int r = 0; r < 4; ++r)
        #pragma unroll
        for (int c = 0; c < 4; ++c) acc[r][c] = 0.f;

    for (int k = 0; k < 128; k += 4) {
        int kc = k >> 2;
        float4 w0 = *(const float4*)&Wl[k][tc * 4];
        float4 w1 = *(const float4*)&Wl[k + 1][tc * 4];
        float4 w2 = *(const float4*)&Wl[k + 2][tc * 4];
        float4 w3 = *(const float4*)&Wl[k + 3][tc * 4];
        #pragma unroll
        for (int r = 0; r < 4; ++r) {
            int row = r0 + r;
            int ch = (kc + row + (row >> 2)) & 31;
            float4 xv = Xs4[row * 32 + ch];
            acc[r][0] += xv.x * w0.x + xv.y * w1.x + xv.z * w2.x + xv.w * w3.x;
            acc[r][1] += xv.x * w0.y + xv.y * w1.y + xv.z * w2.y + xv.w * w3.y;
            acc[r][2] += xv.x * w0.z + xv.y * w1.z + xv.z * w2.z + xv.w * w3.z;
            acc[r][3] += xv.x * w0.w + xv.y * w1.w + xv.z * w2.w + xv.w * w3.w;
        }
    }

    float s0 = a_src[head * 64 + tc * 4 + 0], s1 = a_src[head * 64 + tc * 4 + 1];
    float s2 = a_src[head * 64 + tc * 4 + 2], s3 = a_src[head * 64 + tc * 4 + 3];
    float d0 = a_dst[head * 64 + tc * 4 + 0], d1 = a_dst[head * 64 + tc * 4 + 1];
    float d2 = a_dst[head * 64 + tc * 4 + 2], d3 = a_dst[head * 64 + tc * 4 + 3];

    #pragma unroll
    for (int r = 0; r < 4; ++r) {
        int g = row0 + r0 + r;
        float ps = acc[r][0] * s0 + acc[r][1] * s1 + acc[r][2] * s2 + acc[r][3] * s3;
        float pd = acc[r][0] * d0 + acc[r][1] * d1 + acc[r][2] * d2 + acc[r][3] * d3;
        #pragma unroll
        for (int m = 1; m < 16; m <<= 1) {
            ps += __shfl_xor(ps, m, 64);
            pd += __shfl_xor(pd, m, 64);
        }
        if (g < N_NODES) {
            ushort4 pk;
            pk.x = f2bf(acc[r][0]); pk.y = f2bf(acc[r][1]);
            pk.z = f2bf(acc[r][2]); pk.w = f2bf(acc[r][3]);
            *(ushort4*)&Y[(size_t)g * 128 + head * 64 + tc * 4] = pk;
            if (tc == 0) { als[g * 2 + head] = ps; ald[g * 2 + head] = pd; }
        }
    }
}

// ---------------- GAT aggregation: 4-edge-per-wave gather, dwordx4 loads ----------------
// Wave = 4 groups x 16 lanes. Group g processes edge j0+4i+g; lane (lg=lane&15) loads
// 16B = channels [8*lg, 8*lg+8) of the source row. Weights broadcast via shfl.
// Cross-group shfl_xor reduce at the end; self-loop added once after reduce.
__device__ __forceinline__ void agg4(
    const unsigned short* __restrict__ xp, const float2* __restrict__ als2,
    const float2* __restrict__ ald2, const int* __restrict__ rp,
    const int* __restrict__ ssrc, int node, int lane, float* r /*8*/) {
    const uint4* xp4 = (const uint4*)xp;       // row = 16 x uint4 (256 B)
    int lg = lane & 15, grp = lane >> 4;
    float2 adv = ald2[node];
    float2 asf = als2[node];
    float ws0 = __expf(lrelu02(asf.x + adv.x));
    float ws1 = __expf(lrelu02(asf.y + adv.y));
    float a0 = 0.f, a1 = 0.f, a2 = 0.f, a3 = 0.f, a4 = 0.f, a5 = 0.f, a6 = 0.f, a7 = 0.f;
    float dp0 = 0.f, dp1 = 0.f;
    int start = rp[node], end = rp[node + 1];
    for (int j0 = start; j0 < end; j0 += 64) {
        int rem = end - j0;
        int sv = 0; float w0v = 0.f, w1v = 0.f;
        if (lane < rem) {
            sv = ssrc[j0 + lane];
            float2 a = als2[sv];
            w0v = __expf(lrelu02(a.x + adv.x));
            w1v = __expf(lrelu02(a.y + adv.y));
        }
        dp0 += w0v; dp1 += w1v;
        int len = rem < 64 ? rem : 64;
        int nit = (len + 3) >> 2;              // 4 edges per iteration
        int i = 0;
        for (; i + 2 <= nit; i += 2) {         // 2x unroll: 8 edges / 2 loads in flight
            int la = 4 * i + grp, lb = la + 4;
            int sa = __shfl(sv, la, 64);
            int sb = __shfl(sv, lb, 64);
            float wa0 = __shfl(w0v, la, 64), wa1 = __shfl(w1v, la, 64);
            float wb0 = __shfl(w0v, lb, 64), wb1 = __shfl(w1v, lb, 64);
            uint4 va = xp4[sa * 16 + lg];
            uint4 vb = xp4[sb * 16 + lg];
            float wa = (lg >= 8) ? wa1 : wa0;
            float wb = (lg >= 8) ? wb1 : wb0;
            a0 = fmaf(wa, __uint_as_float(va.x << 16), a0);
            a1 = fmaf(wa, __uint_as_float(va.x & 0xffff0000u), a1);
            a2 = fmaf(wa, __uint_as_float(va.y << 16), a2);
            a3 = fmaf(wa, __uint_as_float(va.y & 0xffff0000u), a3);
            a4 = fmaf(wa, __uint_as_float(va.z << 16), a4);
            a5 = fmaf(wa, __uint_as_float(va.z & 0xffff0000u), a5);
            a6 = fmaf(wa, __uint_as_float(va.w << 16), a6);
            a7 = fmaf(wa, __uint_as_float(va.w & 0xffff0000u), a7);
            a0 = fmaf(wb, __uint_as_float(vb.x << 16), a0);
            a1 = fmaf(wb, __uint_as_float(vb.x & 0xffff0000u), a1);
            a2 = fmaf(wb, __uint_as_float(vb.y << 16), a2);
            a3 = fmaf(wb, __uint_as_float(vb.y & 0xffff0000u), a3);
            a4 = fmaf(wb, __uint_as_float(vb.z << 16), a4);
            a5 = fmaf(wb, __uint_as_float(vb.z & 0xffff0000u), a5);
            a6 = fmaf(wb, __uint_as_float(vb.w << 16), a6);
            a7 = fmaf(wb, __uint_as_float(vb.w & 0xffff0000u), a7);
        }
        if (i < nit) {
            int la = 4 * i + grp;
            int sa = __shfl(sv, la, 64);
            float wa0 = __shfl(w0v, la, 64), wa1 = __shfl(w1v, la, 64);
            uint4 va = xp4[sa * 16 + lg];
            float wa = (lg >= 8) ? wa1 : wa0;   // 0 for out-of-range edges
            a0 = fmaf(wa, __uint_as_float(va.x << 16), a0);
            a1 = fmaf(wa, __uint_as_float(va.x & 0xffff0000u), a1);
            a2 = fmaf(wa, __uint_as_float(va.y << 16), a2);
            a3 = fmaf(wa, __uint_as_float(va.y & 0xffff0000u), a3);
            a4 = fmaf(wa, __uint_as_float(va.z << 16), a4);
            a5 = fmaf(wa, __uint_as_float(va.z & 0xffff0000u), a5);
            a6 = fmaf(wa, __uint_as_float(va.w << 16), a6);
            a7 = fmaf(wa, __uint_as_float(va.w & 0xffff0000u), a7);
        }
    }
    // cross-group reduce: every lane ends with the full edge-sum for its 8 channels
    #pragma unroll
    for (int m = 16; m < 64; m <<= 1) {
        a0 += __shfl_xor(a0, m, 64); a1 += __shfl_xor(a1, m, 64);
        a2 += __shfl_xor(a2, m, 64); a3 += __shfl_xor(a3, m, 64);
        a4 += __shfl_xor(a4, m, 64); a5 += __shfl_xor(a5, m, 64);
        a6 += __shfl_xor(a6, m, 64); a7 += __shfl_xor(a7, m, 64);
    }
    #pragma unroll
    for (int m = 1; m < 64; m <<= 1) {
        dp0 += __shfl_xor(dp0, m, 64);
        dp1 += __shfl_xor(dp1, m, 64);
    }
    // self loop (added once, after the cross-group reduce)
    uint4 v = xp4[node * 16 + lg];
    float wss = (lg >= 8) ? ws1 : ws0;
    a0 = fmaf(wss, __uint_as_float(v.x << 16), a0);
    a1 = fmaf(wss, __uint_as_float(v.x & 0xffff0000u), a1);
    a2 = fmaf(wss, __uint_as_float(v.y << 16), a2);
    a3 = fmaf(wss, __uint_as_float(v.y & 0xffff0000u), a3);
    a4 = fmaf(wss, __uint_as_float(v.z << 16), a4);
    a5 = fmaf(wss, __uint_as_float(v.z & 0xffff0000u), a5);
    a6 = fmaf(wss, __uint_as_float(v.w << 16), a6);
    a7 = fmaf(wss, __uint_as_float(v.w & 0xffff0000u), a7);
    float inv = 1.f / (((lg >= 8) ? dp1 + ws1 : dp0 + ws0) + 1e-16f);
    r[0] = a0 * inv; r[1] = a1 * inv; r[2] = a2 * inv; r[3] = a3 * inv;
    r[4] = a4 * inv; r[5] = a5 * inv; r[6] = a6 * inv; r[7] = a7 * inv;
}

// XCD-partitioned aggregation: graph A on XCDs 0-3, graph B on XCDs 4-7
// (blockIdx -> XCD assumed round-robin %8; wrong mapping only costs speed).
// grid = 25000 blocks x 256 thr (4 waves = 4 nodes each).
__global__ __launch_bounds__(256) void k_agg(
    const unsigned short* __restrict__ xpA, const float2* __restrict__ alsA, const float2* __restrict__ aldA,
    const int* __restrict__ rp1, const int* __restrict__ ssrc1, unsigned short* __restrict__ outA,
    const unsigned short* __restrict__ xpB, const float2* __restrict__ alsB, const float2* __restrict__ aldB,
    const int* __restrict__ rp2, const int* __restrict__ ssrc2, unsigned short* __restrict__ outB,
    const float* __restrict__ bias) {
    int x = blockIdx.x;
    int xcd = x & 7;
    int g = xcd >> 2;                           // graph = XCD half
    int j = (x >> 3) * 4 + (xcd & 3);           // per-graph block id in [0,12500)
    const unsigned short* xp = g ? xpB : xpA;
    const float2* als = g ? alsB : alsA;
    const float2* ald = g ? aldB : aldA;
    const int* rp = g ? rp2 : rp1;
    const int* ssrc = g ? ssrc2 : ssrc1;
    unsigned short* out = g ? outB : outA;
    int node = j * 4 + (threadIdx.x >> 6);
    int lane = threadIdx.x & 63;
    int lg = lane & 15;
    float r[8];
    agg4(xp, als, ald, rp, ssrc, node, lane, r);
    float4 b0 = *(const float4*)&bias[8 * lg];
    float4 b1 = *(const float4*)&bias[8 * lg + 4];
    float o0 = fmaxf(r[0] + b0.x, 0.f), o1 = fmaxf(r[1] + b0.y, 0.f);
    float o2 = fmaxf(r[2] + b0.z, 0.f), o3 = fmaxf(r[3] + b0.w, 0.f);
    float o4 = fmaxf(r[4] + b1.x, 0.f), o5 = fmaxf(r[5] + b1.y, 0.f);
    float o6 = fmaxf(r[6] + b1.z, 0.f), o7 = fmaxf(r[7] + b1.w, 0.f);
    if ((lane >> 4) == 0) {                    // group 0 writes the bf16 row (256 B)
        uint4 o;
        o.x = (unsigned)f2bf(o0) | ((unsigned)f2bf(o1) << 16);
        o.y = (unsigned)f2bf(o2) | ((unsigned)f2bf(o3) << 16);
        o.z = (unsigned)f2bf(o4) | ((unsigned)f2bf(o5) << 16);
        o.w = (unsigned)f2bf(o6) | ((unsigned)f2bf(o7) << 16);
        ((uint4*)out)[node * 16 + lg] = o;
    }
}

// ---------------- streaming pairwise distance + hi-histogram ----------------
// block = 256 thr = 16 groups x 16 lanes; group handles one node (reads 2 x 256 B rows).
__global__ __launch_bounds__(256) void k_dist(
    const unsigned short* __restrict__ outA, const unsigned short* __restrict__ outB,
    float* __restrict__ sim, int* __restrict__ hist) {
    int t = threadIdx.x;
    int node = blockIdx.x * 16 + (t >> 4);
    int lg = t & 15;
    uint4 va = ((const uint4*)outA)[node * 16 + lg];
    uint4 vb = ((const uint4*)outB)[node * 16 + lg];
    float p = 0.f;
    {
        float d;
        d = __uint_as_float(va.x << 16)         - __uint_as_float(vb.x << 16)         + 1e-6f; p = fmaf(d, d, p);
        d = __uint_as_float(va.x & 0xffff0000u) - __uint_as_float(vb.x & 0xffff0000u) + 1e-6f; p = fmaf(d, d, p);
        d = __uint_as_float(va.y << 16)         - __uint_as_float(vb.y << 16)         + 1e-6f; p = fmaf(d, d, p);
        d = __uint_as_float(va.y & 0xffff0000u) - __uint_as_float(vb.y & 0xffff0000u) + 1e-6f; p = fmaf(d, d, p);
        d = __uint_as_float(va.z << 16)         - __uint_as_float(vb.z << 16)         + 1e-6f; p = fmaf(d, d, p);
        d = __uint_as_float(va.z & 0xffff0000u) - __uint_as_float(vb.z & 0xffff0000u) + 1e-6f; p = fmaf(d, d, p);
        d = __uint_as_float(va.w << 16)         - __uint_as_float(vb.w << 16)         + 1e-6f; p = fmaf(d, d, p);
        d = __uint_as_float(va.w & 0xffff0000u) - __uint_as_float(vb.w & 0xffff0000u) + 1e-6f; p = fmaf(d, d, p);
    }
    #pragma unroll
    for (int m = 1; m < 16; m <<= 1) p += __shfl_xor(p, m, 64);  // within 16-lane group
    if (lg == 0) {
        float sv = sqrtf(p);
        sim[node] = sv;
        atomicAdd(&hist[__float_as_uint(sv) >> 16], 1);
    }
}

// ---------------- fused two-level radix select (one block) ----------------
// state: [2]=threshold key T, [3]=numGreater
__global__ __launch_bounds__(1024) void k_select2(
    const float* __restrict__ sim, const int* __restrict__ hhi,
    int* __restrict__ hlo, int* __restrict__ state) {
    __shared__ int lds[1024];
    __shared__ int sbin, scnt;
    int t = threadIdx.x;
    int base = t * 64;
    int local = 0;
    for (int i = 0; i < 64; ++i) local += hhi[base + i];
    lds[t] = local;
    __syncthreads();
    for (int off = 1; off < 1024; off <<= 1) {   // suffix-inclusive scan from top
        int add = (t + off < 1024) ? lds[t + off] : 0;
        __syncthreads();
        lds[t] += add;
        __syncthreads();
    }
    int incl = lds[t];
    int above = (t < 1023) ? lds[t + 1] : 0;
    if (above < TOPK && incl >= TOPK) {
        int c = above;
        for (int b = 63; b >= 0; --b) {
            int h = hhi[base + b];
            if (c + h >= TOPK) { sbin = base + b; scnt = c; break; }
            c += h;
        }
    }
    __syncthreads();
    int hb = sbin, cA = scnt;
    // lo-level histogram of keys in boundary hi-bin (block-internal)
    for (int i = t; i < N_NODES; i += 1024) {
        unsigned key = __float_as_uint(sim[i]);
        if ((int)(key >> 16) == hb) atomicAdd(&hlo[key & 0xFFFF], 1);
    }
    __threadfence();
    __syncthreads();
    int K2 = TOPK - cA;
    local = 0;
    for (int i = 0; i < 64; ++i) local += hlo[base + i];
    lds[t] = local;
    __syncthreads();
    for (int off = 1; off < 1024; off <<= 1) {
        int add = (t + off < 1024) ? lds[t + off] : 0;
        __syncthreads();
        lds[t] += add;
        __syncthreads();
    }
    incl = lds[t];
    above = (t < 1023) ? lds[t + 1] : 0;
    if (above < K2 && incl >= K2) {
        int c = above;
        for (int b = 63; b >= 0; --b) {
            int h = hlo[base + b];
            if (c + h >= K2) {
                state[2] = (int)((((unsigned)hb) << 16) | (unsigned)(base + b));
                state[3] = cA + c;
                break;
            }
            c += h;
        }
    }
}

// ---------------- collect + sort 512 + full MLP head (one block) ----------------
__global__ __launch_bounds__(512) void k_sort_mlp(
    const float* __restrict__ sim, const int* __restrict__ state,
    const float* __restrict__ fc1_w, const float* __restrict__ fc1_b,
    const float* __restrict__ ln1_w, const float* __restrict__ ln1_b,
    const float* __restrict__ fc2_w, const float* __restrict__ fc2_b,
    const float* __restrict__ ln2_w, const float* __restrict__ ln2_b,
    const float* __restrict__ fc3_w, const float* __restrict__ fc3_b,
    float* __restrict__ outp) {
    __shared__ float s[512];
    __shared__ float h1p[4][128];
    __shared__ float h1[128];
    __shared__ float h2[64];
    __shared__ float stats[2];
    __shared__ int cnt;
    int t = threadIdx.x;
    unsigned T = (unsigned)state[2];
    int nG = state[3];
    if (t == 0) cnt = 0;
    __syncthreads();
    for (int i = t; i < N_NODES; i += 512) {
        float v = sim[i];
        if (__float_as_uint(v) > T) { int p = atomicAdd(&cnt, 1); s[p] = v; }
    }
    __syncthreads();
    if (t >= nG) s[t] = __uint_as_float(T);   // pad exact-threshold ties
    __syncthreads();
    for (int k = 2; k <= 512; k <<= 1)
        for (int j = k >> 1; j > 0; j >>= 1) {
            int ixj = t ^ j;
            if (ixj > t) {
                float a = s[t], b = s[ixj];
                bool up = ((t & k) == 0);
                if ((a > b) == up) { s[t] = b; s[ixj] = a; }
            }
            __syncthreads();
        }
    // s ascending; topv[i] = s[511-i]
    {
        int o = t & 127, seg = t >> 7;
        float acc = 0.f;
        for (int i = seg * 128; i < seg * 128 + 128; ++i)
            acc += s[511 - i] * fc1_w[i * 128 + o];
        h1p[seg][o] = acc;
    }
    __syncthreads();
    if (t < 128) h1[t] = fc1_b[t] + h1p[0][t] + h1p[1][t] + h1p[2][t] + h1p[3][t];
    __syncthreads();
    if (t == 0) {
        float mu = 0.f;
        for (int i = 0; i < 128; ++i) mu += h1[i];
        mu *= (1.f / 128.f);
        float var = 0.f;
        for (int i = 0; i < 128; ++i) { float d = h1[i] - mu; var += d * d; }
        var *= (1.f / 128.f);
        stats[0] = mu; stats[1] = rsqrtf(var + 1e-5f);
    }
    __syncthreads();
    if (t < 128) h1[t] = fmaxf((h1[t] - stats[0]) * stats[1] * ln1_w[t] + ln1_b[t], 0.f);
    __syncthreads();
    if (t < 64) {
        float acc = fc2_b[t];
        for (int i = 0; i < 128; ++i) acc += h1[i] * fc2_w[i * 64 + t];
        h2[t] = acc;
    }
    __syncthreads();
    if (t == 0) {
        float mu = 0.f;
        for (int i = 0; i < 64; ++i) mu += h2[i];
        mu *= (1.f / 64.f);
        float var = 0.f;
        for (int i = 0; i < 64; ++i) { float d = h2[i] - mu; var += d * d; }
        var *= (1.f / 64.f);
        stats[0] = mu; stats[1] = rsqrtf(var + 1e-5f);
    }
    __syncthreads();
    if (t < 64) h2[t] = fmaxf((h2[t] - stats[0]) * stats[1] * ln2_w[t] + ln2_b[t], 0.f);
    __syncthreads();
    if (t == 0) {
        float z = fc3_b[0];
        for (int i = 0; i < 64; ++i) z += h2[i] * fc3_w[i];
        outp[0] = 1.f / (1.f + expf(-z));
    }
}

extern "C" void kernel_launch(void* const* d_in, const int* in_sizes, int n_in,
                              void* d_out, int out_size, void* d_ws, size_t ws_size,
                              hipStream_t stream) {
    const float* x1 = (const float*)d_in[0];
    const float* x2 = (const float*)d_in[1];
    const int* ei1 = (const int*)d_in[2];
    const int* ei2 = (const int*)d_in[3];
    const float* W1 = (const float*)d_in[4];
    const float* as1 = (const float*)d_in[5];
    const float* ad1 = (const float*)d_in[6];
    const float* b1 = (const float*)d_in[7];
    const float* W2 = (const float*)d_in[8];
    const float* as2 = (const float*)d_in[9];
    const float* ad2 = (const float*)d_in[10];
    const float* b2 = (const float*)d_in[11];
    const float* fc1_w = (const float*)d_in[12];
    const float* fc1_b = (const float*)d_in[13];
    const float* ln1_w = (const float*)d_in[14];
    const float* ln1_b = (const float*)d_in[15];
    const float* fc2_w = (const float*)d_in[16];
    const float* fc2_b = (const float*)d_in[17];
    const float* ln2_w = (const float*)d_in[18];
    const float* ln2_b = (const float*)d_in[19];
    const float* fc3_w = (const float*)d_in[20];
    const float* fc3_b = (const float*)d_in[21];
    float* outp = (float*)d_out;

    char* ws = (char*)d_ws;
    size_t off = 0;
    auto alloc = [&](size_t bytes) -> void* {
        void* p = ws + off;
        off = (off + bytes + 255) & ~(size_t)255;
        return p;
    };
    unsigned short* xpA = (unsigned short*)alloc((size_t)N_NODES * 128 * 2);
    unsigned short* xpB = (unsigned short*)alloc((size_t)N_NODES * 128 * 2);
    unsigned short* tmpA = (unsigned short*)alloc((size_t)N_NODES * 128 * 2);
    unsigned short* tmpB = (unsigned short*)alloc((size_t)N_NODES * 128 * 2);
    int* ssrc1  = (int*)alloc((size_t)N_EDGES * 4);
    int* ssrc2  = (int*)alloc((size_t)N_EDGES * 4);
    int* rp1    = (int*)alloc((size_t)(N_NODES + 1) * 4);
    int* rp2    = (int*)alloc((size_t)(N_NODES + 1) * 4);
    float2* alsA = (float2*)alloc((size_t)N_NODES * 8);
    float2* aldA = (float2*)alloc((size_t)N_NODES * 8);
    float2* alsB = (float2*)alloc((size_t)N_NODES * 8);
    float2* aldB = (float2*)alloc((size_t)N_NODES * 8);
    int* part1 = (int*)alloc(64 * 4);
    int* part2 = (int*)alloc(64 * 4);
    int* bo1   = (int*)alloc(64 * 4);
    int* bo2   = (int*)alloc(64 * 4);
    float* sim = (float*)alloc((size_t)N_NODES * 4);
    // ---- zero-initialized region (one memset) ----
    char* zbase = ws + off;
    int* cnt1 = (int*)alloc((size_t)N_NODES * 4);
    int* cnt2 = (int*)alloc((size_t)N_NODES * 4);
    int* cur1 = (int*)alloc((size_t)N_NODES * 4);
    int* cur2 = (int*)alloc((size_t)N_NODES * 4);
    int* hist1 = (int*)alloc(65536 * 4);
    int* hist2 = (int*)alloc(65536 * 4);
    int* state = (int*)alloc(64);
    size_t zsize = (size_t)((ws + off) - zbase);
    hipMemsetAsync(zbase, 0, zsize, stream);

    // CSR for both graphs
    k_count2<<<6250, 256, 0, stream>>>(ei1, ei2, cnt1, cnt2);
    k_scan1<<<dim3(49, 2), 1024, 0, stream>>>(cnt1, cnt2, rp1, rp2, part1, part2);
    k_scan2<<<1, 128, 0, stream>>>(part1, part2, bo1, bo2, rp1, rp2);
    k_scan3<<<dim3(49, 2), 1024, 0, stream>>>(rp1, rp2, bo1, bo2);
    k_scatter2<<<6250, 256, 0, stream>>>(ei1, ei2, rp1, rp2, cur1, cur2, ssrc1, ssrc2);

    dim3 ggrid(782, 2, 2);
    // layer 1 (both graphs); agg partitioned: graph A -> XCD 0-3, graph B -> XCD 4-7
    k_gemm_att<0><<<ggrid, 256, 0, stream>>>(x1, x2, W1, as1, ad1, xpA, xpB, alsA, aldA, alsB, aldB);
    k_agg<<<25000, 256, 0, stream>>>(xpA, alsA, aldA, rp1, ssrc1, tmpA,
                                     xpB, alsB, aldB, rp2, ssrc2, tmpB, b1);
    // layer 2 (both graphs, bf16 input); partitioned agg writes rows, then streaming distance
    k_gemm_att<1><<<ggrid, 256, 0, stream>>>(tmpA, tmpB, W2, as2, ad2,
                                             xpA, xpB, alsA, aldA, alsB, aldB);
    k_agg<<<25000, 256, 0, stream>>>(xpA, alsA, aldA, rp1, ssrc1, tmpA,
                                     xpB, alsB, aldB, rp2, ssrc2, tmpB, b2);
    k_dist<<<3125, 256, 0, stream>>>(tmpA, tmpB, sim, hist1);

    // fused exact top-512 + MLP head
    k_select2<<<1, 1024, 0, stream>>>(sim, hist1, hist2, state);
    k_sort_mlp<<<1, 512, 0, stream>>>(sim, state, fc1_w, fc1_b, ln1_w, ln1_b,
                                      fc2_w, fc2_b, ln2_w, ln2_b, fc3_w, fc3_b, outp);
}

// Round 12
// 650.814 us; speedup vs baseline: 1.2449x; 1.2449x over previous
//
#include <hip/hip_runtime.h>
#include <hip/hip_bf16.h>
#include <math.h>

#define N_NODES 50000
#define N_EDGES 800000
#define TOPK 512

__device__ __forceinline__ float lrelu02(float v) { return v > 0.f ? v : 0.2f * v; }

__device__ __forceinline__ unsigned short f2bf(float f) {
    unsigned u = __float_as_uint(f);
    u += 0x7fffu + ((u >> 16) & 1u);       // RNE
    return (unsigned short)(u >> 16);
}

// ---------------- CSR build (counting sort by dst), both graphs ----------------
__global__ void k_count2(const int* __restrict__ ei1, const int* __restrict__ ei2,
                         int* __restrict__ cnt1, int* __restrict__ cnt2) {
    int e = blockIdx.x * 256 + threadIdx.x;
    if (e < N_EDGES) atomicAdd(&cnt1[ei1[N_EDGES + e]], 1);
    else if (e < 2 * N_EDGES) atomicAdd(&cnt2[ei2[e]], 1);  // ei2[E + (e-E)] == ei2[e]
}

__global__ __launch_bounds__(1024) void k_scan1(const int* __restrict__ cnt1, const int* __restrict__ cnt2,
                                                int* __restrict__ rp1, int* __restrict__ rp2,
                                                int* __restrict__ part1, int* __restrict__ part2) {
    __shared__ int lds[1024];
    int g = blockIdx.y;
    const int* cnt = g ? cnt2 : cnt1;
    int* rp = g ? rp2 : rp1;
    int* part = g ? part2 : part1;
    int t = threadIdx.x;
    int i = blockIdx.x * 1024 + t;
    int v = (i < N_NODES) ? cnt[i] : 0;
    lds[t] = v;
    __syncthreads();
    for (int off = 1; off < 1024; off <<= 1) {
        int add = (t >= off) ? lds[t - off] : 0;
        __syncthreads();
        lds[t] += add;
        __syncthreads();
    }
    if (i < N_NODES) rp[i] = lds[t] - v;   // block-local exclusive
    if (t == 1023) part[blockIdx.x] = lds[1023];
}

__global__ __launch_bounds__(128) void k_scan2(const int* __restrict__ part1, const int* __restrict__ part2,
                                               int* __restrict__ bo1, int* __restrict__ bo2,
                                               int* __restrict__ rp1, int* __restrict__ rp2) {
    int t = threadIdx.x, g = t >> 6, lane = t & 63;
    const int* part = g ? part2 : part1;
    int* bo = g ? bo2 : bo1;
    int v = (lane < 49) ? part[lane] : 0;
    int p = v;
    for (int d = 1; d < 64; d <<= 1) { int u = __shfl_up(p, d, 64); if (lane >= d) p += u; }
    if (lane < 49) bo[lane] = p - v;
    if (lane == 0) (g ? rp2 : rp1)[N_NODES] = N_EDGES;
}

__global__ __launch_bounds__(1024) void k_scan3(int* __restrict__ rp1, int* __restrict__ rp2,
                                                const int* __restrict__ bo1, const int* __restrict__ bo2) {
    int g = blockIdx.y;
    int* rp = g ? rp2 : rp1;
    int add = (g ? bo2 : bo1)[blockIdx.x];
    int i = blockIdx.x * 1024 + threadIdx.x;
    if (i < N_NODES) rp[i] += add;
}

__global__ void k_scatter2(const int* __restrict__ ei1, const int* __restrict__ ei2,
                           const int* __restrict__ rp1, const int* __restrict__ rp2,
                           int* __restrict__ cur1, int* __restrict__ cur2,
                           int* __restrict__ ssrc1, int* __restrict__ ssrc2) {
    int e = blockIdx.x * 256 + threadIdx.x;
    if (e < N_EDGES) {
        int src = ei1[e], dst = ei1[N_EDGES + e];
        ssrc1[rp1[dst] + atomicAdd(&cur1[dst], 1)] = src;
    } else if (e < 2 * N_EDGES) {
        int ee = e - N_EDGES;
        int src = ei2[ee], dst = ei2[e];
        ssrc2[rp2[dst] + atomicAdd(&cur2[dst], 1)] = src;
    }
}

// ---------------- GEMM (x @ W) with fused attention logits, bf16 output ----------------
// IN_BF16: input rows are bf16 (layer-2, reads tmp) vs f32 (layer-1).
template<int IN_BF16>
__global__ __launch_bounds__(256) void k_gemm_att(
    const void* __restrict__ XA_, const void* __restrict__ XB_, const float* __restrict__ W,
    const float* __restrict__ a_src, const float* __restrict__ a_dst,
    unsigned short* __restrict__ YA, unsigned short* __restrict__ YB,
    float2* __restrict__ alsA, float2* __restrict__ aldA,
    float2* __restrict__ alsB, float2* __restrict__ aldB) {
    __shared__ __align__(16) float Xs[64][128];
    __shared__ __align__(16) float Wl[128][64];
    int t = threadIdx.x;
    int head = blockIdx.y;
    int row0 = blockIdx.x * 64;
    const void* X = blockIdx.z ? XB_ : XA_;
    unsigned short* Y = blockIdx.z ? YB : YA;
    float* als = (float*)(blockIdx.z ? alsB : alsA);
    float* ald = (float*)(blockIdx.z ? aldB : aldA);

    const float4* W4 = (const float4*)W;
    float4* Wl4 = (float4*)Wl;
    #pragma unroll
    for (int i = 0; i < 8; ++i) {
        int e = i * 256 + t;
        int k = e >> 4, cc = e & 15;
        Wl4[k * 16 + cc] = W4[k * 32 + head * 16 + cc];
    }
    float4* Xs4 = (float4*)Xs;
    if (IN_BF16) {
        const uint4* Xb = (const uint4*)X;     // row = 16 x (8 bf16)
        #pragma unroll
        for (int i = 0; i < 4; ++i) {
            int e = i * 256 + t;               // 0..1023
            int r = e >> 4, c8 = e & 15;
            int g = row0 + r;
            uint4 v = make_uint4(0u, 0u, 0u, 0u);
            if (g < N_NODES) v = Xb[g * 16 + c8];
            float4 f0 = make_float4(__uint_as_float(v.x << 16), __uint_as_float(v.x & 0xffff0000u),
                                    __uint_as_float(v.y << 16), __uint_as_float(v.y & 0xffff0000u));
            float4 f1 = make_float4(__uint_as_float(v.z << 16), __uint_as_float(v.z & 0xffff0000u),
                                    __uint_as_float(v.w << 16), __uint_as_float(v.w & 0xffff0000u));
            int c0 = c8 * 2, c1 = c0 + 1;
            Xs4[r * 32 + ((c0 + r + (r >> 2)) & 31)] = f0;
            Xs4[r * 32 + ((c1 + r + (r >> 2)) & 31)] = f1;
        }
    } else {
        const float4* X4 = (const float4*)X;   // row = 32 float4
        #pragma unroll
        for (int i = 0; i < 8; ++i) {
            int e = i * 256 + t;               // 0..2047
            int r = e >> 5, c = e & 31;
            int g = row0 + r;
            float4 v = make_float4(0.f, 0.f, 0.f, 0.f);
            if (g < N_NODES) v = X4[(size_t)g * 32 + c];
            int ch = (c + r + (r >> 2)) & 31;  // bank-conflict swizzle
            Xs4[r * 32 + ch] = v;
        }
    }
    __syncthreads();

    int tc = t & 15, tr = t >> 4;
    int r0 = tr * 4;
    float acc[4][4];
    #pragma unroll
    for (int r = 0; r < 4; ++r)
        #pragma unroll
        for (int c = 0; c < 4; ++c) acc[r][c] = 0.f;

    for (int k = 0; k < 128; k += 4) {
        int kc = k >> 2;
        float4 w0 = *(const float4*)&Wl[k][tc * 4];
        float4 w1 = *(const float4*)&Wl[k + 1][tc * 4];
        float4 w2 = *(const float4*)&Wl[k + 2][tc * 4];
        float4 w3 = *(const float4*)&Wl[k + 3][tc * 4];
        #pragma unroll
        for (int r = 0; r < 4; ++r) {
            int row = r0 + r;
            int ch = (kc + row + (row >> 2)) & 31;
            float4 xv = Xs4[row * 32 + ch];
            acc[r][0] += xv.x * w0.x + xv.y * w1.x + xv.z * w2.x + xv.w * w3.x;
            acc[r][1] += xv.x * w0.y + xv.y * w1.y + xv.z * w2.y + xv.w * w3.y;
            acc[r][2] += xv.x * w0.z + xv.y * w1.z + xv.z * w2.z + xv.w * w3.z;
            acc[r][3] += xv.x * w0.w + xv.y * w1.w + xv.z * w2.w + xv.w * w3.w;
        }
    }

    float s0 = a_src[head * 64 + tc * 4 + 0], s1 = a_src[head * 64 + tc * 4 + 1];
    float s2 = a_src[head * 64 + tc * 4 + 2], s3 = a_src[head * 64 + tc * 4 + 3];
    float d0 = a_dst[head * 64 + tc * 4 + 0], d1 = a_dst[head * 64 + tc * 4 + 1];
    float d2 = a_dst[head * 64 + tc * 4 + 2], d3 = a_dst[head * 64 + tc * 4 + 3];

    #pragma unroll
    for (int r = 0; r < 4; ++r) {
        int g = row0 + r0 + r;
        float ps = acc[r][0] * s0 + acc[r][1] * s1 + acc[r][2] * s2 + acc[r][3] * s3;
        float pd = acc[r][0] * d0 + acc[r][1] * d1 + acc[r][2] * d2 + acc[r][3] * d3;
        #pragma unroll
        for (int m = 1; m < 16; m <<= 1) {
            ps += __shfl_xor(ps, m, 64);
            pd += __shfl_xor(pd, m, 64);
        }
        if (g < N_NODES) {
            ushort4 pk;
            pk.x = f2bf(acc[r][0]); pk.y = f2bf(acc[r][1]);
            pk.z = f2bf(acc[r][2]); pk.w = f2bf(acc[r][3]);
            *(ushort4*)&Y[(size_t)g * 128 + head * 64 + tc * 4] = pk;
            if (tc == 0) { als[g * 2 + head] = ps; ald[g * 2 + head] = pd; }
        }
    }
}

// ---------------- GAT aggregation: 4-edge-per-wave gather, dwordx4 loads ----------------
__device__ __forceinline__ void agg4(
    const unsigned short* __restrict__ xp, const float2* __restrict__ als2,
    const float2* __restrict__ ald2, const int* __restrict__ rp,
    const int* __restrict__ ssrc, int node, int lane, float* r /*8*/) {
    const uint4* xp4 = (const uint4*)xp;       // row = 16 x uint4 (256 B)
    int lg = lane & 15, grp = lane >> 4;
    float2 adv = ald2[node];
    float2 asf = als2[node];
    float ws0 = __expf(lrelu02(asf.x + adv.x));
    float ws1 = __expf(lrelu02(asf.y + adv.y));
    float a0 = 0.f, a1 = 0.f, a2 = 0.f, a3 = 0.f, a4 = 0.f, a5 = 0.f, a6 = 0.f, a7 = 0.f;
    float dp0 = 0.f, dp1 = 0.f;
    int start = rp[node], end = rp[node + 1];
    for (int j0 = start; j0 < end; j0 += 64) {
        int rem = end - j0;
        int sv = 0; float w0v = 0.f, w1v = 0.f;
        if (lane < rem) {
            sv = ssrc[j0 + lane];
            float2 a = als2[sv];
            w0v = __expf(lrelu02(a.x + adv.x));
            w1v = __expf(lrelu02(a.y + adv.y));
        }
        dp0 += w0v; dp1 += w1v;
        int len = rem < 64 ? rem : 64;
        int nit = (len + 3) >> 2;              // 4 edges per iteration
        int i = 0;
        for (; i + 2 <= nit; i += 2) {         // 2x unroll: 8 edges / 2 loads in flight
            int la = 4 * i + grp, lb = la + 4;
            int sa = __shfl(sv, la, 64);
            int sb = __shfl(sv, lb, 64);
            float wa0 = __shfl(w0v, la, 64), wa1 = __shfl(w1v, la, 64);
            float wb0 = __shfl(w0v, lb, 64), wb1 = __shfl(w1v, lb, 64);
            uint4 va = xp4[sa * 16 + lg];
            uint4 vb = xp4[sb * 16 + lg];
            float wa = (lg >= 8) ? wa1 : wa0;
            float wb = (lg >= 8) ? wb1 : wb0;
            a0 = fmaf(wa, __uint_as_float(va.x << 16), a0);
            a1 = fmaf(wa, __uint_as_float(va.x & 0xffff0000u), a1);
            a2 = fmaf(wa, __uint_as_float(va.y << 16), a2);
            a3 = fmaf(wa, __uint_as_float(va.y & 0xffff0000u), a3);
            a4 = fmaf(wa, __uint_as_float(va.z << 16), a4);
            a5 = fmaf(wa, __uint_as_float(va.z & 0xffff0000u), a5);
            a6 = fmaf(wa, __uint_as_float(va.w << 16), a6);
            a7 = fmaf(wa, __uint_as_float(va.w & 0xffff0000u), a7);
            a0 = fmaf(wb, __uint_as_float(vb.x << 16), a0);
            a1 = fmaf(wb, __uint_as_float(vb.x & 0xffff0000u), a1);
            a2 = fmaf(wb, __uint_as_float(vb.y << 16), a2);
            a3 = fmaf(wb, __uint_as_float(vb.y & 0xffff0000u), a3);
            a4 = fmaf(wb, __uint_as_float(vb.z << 16), a4);
            a5 = fmaf(wb, __uint_as_float(vb.z & 0xffff0000u), a5);
            a6 = fmaf(wb, __uint_as_float(vb.w << 16), a6);
            a7 = fmaf(wb, __uint_as_float(vb.w & 0xffff0000u), a7);
        }
        if (i < nit) {
            int la = 4 * i + grp;
            int sa = __shfl(sv, la, 64);
            float wa0 = __shfl(w0v, la, 64), wa1 = __shfl(w1v, la, 64);
            uint4 va = xp4[sa * 16 + lg];
            float wa = (lg >= 8) ? wa1 : wa0;   // 0 for out-of-range edges
            a0 = fmaf(wa, __uint_as_float(va.x << 16), a0);
            a1 = fmaf(wa, __uint_as_float(va.x & 0xffff0000u), a1);
            a2 = fmaf(wa, __uint_as_float(va.y << 16), a2);
            a3 = fmaf(wa, __uint_as_float(va.y & 0xffff0000u), a3);
            a4 = fmaf(wa, __uint_as_float(va.z << 16), a4);
            a5 = fmaf(wa, __uint_as_float(va.z & 0xffff0000u), a5);
            a6 = fmaf(wa, __uint_as_float(va.w << 16), a6);
            a7 = fmaf(wa, __uint_as_float(va.w & 0xffff0000u), a7);
        }
    }
    // cross-group reduce: every lane ends with the full edge-sum for its 8 channels
    #pragma unroll
    for (int m = 16; m < 64; m <<= 1) {
        a0 += __shfl_xor(a0, m, 64); a1 += __shfl_xor(a1, m, 64);
        a2 += __shfl_xor(a2, m, 64); a3 += __shfl_xor(a3, m, 64);
        a4 += __shfl_xor(a4, m, 64); a5 += __shfl_xor(a5, m, 64);
        a6 += __shfl_xor(a6, m, 64); a7 += __shfl_xor(a7, m, 64);
    }
    #pragma unroll
    for (int m = 1; m < 64; m <<= 1) {
        dp0 += __shfl_xor(dp0, m, 64);
        dp1 += __shfl_xor(dp1, m, 64);
    }
    // self loop (added once, after the cross-group reduce)
    uint4 v = xp4[node * 16 + lg];
    float wss = (lg >= 8) ? ws1 : ws0;
    a0 = fmaf(wss, __uint_as_float(v.x << 16), a0);
    a1 = fmaf(wss, __uint_as_float(v.x & 0xffff0000u), a1);
    a2 = fmaf(wss, __uint_as_float(v.y << 16), a2);
    a3 = fmaf(wss, __uint_as_float(v.y & 0xffff0000u), a3);
    a4 = fmaf(wss, __uint_as_float(v.z << 16), a4);
    a5 = fmaf(wss, __uint_as_float(v.z & 0xffff0000u), a5);
    a6 = fmaf(wss, __uint_as_float(v.w << 16), a6);
    a7 = fmaf(wss, __uint_as_float(v.w & 0xffff0000u), a7);
    float inv = 1.f / (((lg >= 8) ? dp1 + ws1 : dp0 + ws0) + 1e-16f);
    r[0] = a0 * inv; r[1] = a1 * inv; r[2] = a2 * inv; r[3] = a3 * inv;
    r[4] = a4 * inv; r[5] = a5 * inv; r[6] = a6 * inv; r[7] = a7 * inv;
}

// XCD-partitioned aggregation: graph A on XCDs 0-3, graph B on XCDs 4-7.
__global__ __launch_bounds__(256) void k_agg(
    const unsigned short* __restrict__ xpA, const float2* __restrict__ alsA, const float2* __restrict__ aldA,
    const int* __restrict__ rp1, const int* __restrict__ ssrc1, unsigned short* __restrict__ outA,
    const unsigned short* __restrict__ xpB, const float2* __restrict__ alsB, const float2* __restrict__ aldB,
    const int* __restrict__ rp2, const int* __restrict__ ssrc2, unsigned short* __restrict__ outB,
    const float* __restrict__ bias) {
    int x = blockIdx.x;
    int xcd = x & 7;
    int g = xcd >> 2;                           // graph = XCD half
    int j = (x >> 3) * 4 + (xcd & 3);           // per-graph block id in [0,12500)
    const unsigned short* xp = g ? xpB : xpA;
    const float2* als = g ? alsB : alsA;
    const float2* ald = g ? aldB : aldA;
    const int* rp = g ? rp2 : rp1;
    const int* ssrc = g ? ssrc2 : ssrc1;
    unsigned short* out = g ? outB : outA;
    int node = j * 4 + (threadIdx.x >> 6);
    int lane = threadIdx.x & 63;
    int lg = lane & 15;
    float r[8];
    agg4(xp, als, ald, rp, ssrc, node, lane, r);
    float4 b0 = *(const float4*)&bias[8 * lg];
    float4 b1 = *(const float4*)&bias[8 * lg + 4];
    float o0 = fmaxf(r[0] + b0.x, 0.f), o1 = fmaxf(r[1] + b0.y, 0.f);
    float o2 = fmaxf(r[2] + b0.z, 0.f), o3 = fmaxf(r[3] + b0.w, 0.f);
    float o4 = fmaxf(r[4] + b1.x, 0.f), o5 = fmaxf(r[5] + b1.y, 0.f);
    float o6 = fmaxf(r[6] + b1.z, 0.f), o7 = fmaxf(r[7] + b1.w, 0.f);
    if ((lane >> 4) == 0) {                    // group 0 writes the bf16 row (256 B)
        uint4 o;
        o.x = (unsigned)f2bf(o0) | ((unsigned)f2bf(o1) << 16);
        o.y = (unsigned)f2bf(o2) | ((unsigned)f2bf(o3) << 16);
        o.z = (unsigned)f2bf(o4) | ((unsigned)f2bf(o5) << 16);
        o.w = (unsigned)f2bf(o6) | ((unsigned)f2bf(o7) << 16);
        ((uint4*)out)[node * 16 + lg] = o;
    }
}

// ---------------- streaming pairwise distance (NO atomics) ----------------
__global__ __launch_bounds__(256) void k_dist(
    const unsigned short* __restrict__ outA, const unsigned short* __restrict__ outB,
    float* __restrict__ sim) {
    int t = threadIdx.x;
    int node = blockIdx.x * 16 + (t >> 4);
    int lg = t & 15;
    uint4 va = ((const uint4*)outA)[node * 16 + lg];
    uint4 vb = ((const uint4*)outB)[node * 16 + lg];
    float p = 0.f;
    {
        float d;
        d = __uint_as_float(va.x << 16)         - __uint_as_float(vb.x << 16)         + 1e-6f; p = fmaf(d, d, p);
        d = __uint_as_float(va.x & 0xffff0000u) - __uint_as_float(vb.x & 0xffff0000u) + 1e-6f; p = fmaf(d, d, p);
        d = __uint_as_float(va.y << 16)         - __uint_as_float(vb.y << 16)         + 1e-6f; p = fmaf(d, d, p);
        d = __uint_as_float(va.y & 0xffff0000u) - __uint_as_float(vb.y & 0xffff0000u) + 1e-6f; p = fmaf(d, d, p);
        d = __uint_as_float(va.z << 16)         - __uint_as_float(vb.z << 16)         + 1e-6f; p = fmaf(d, d, p);
        d = __uint_as_float(va.z & 0xffff0000u) - __uint_as_float(vb.z & 0xffff0000u) + 1e-6f; p = fmaf(d, d, p);
        d = __uint_as_float(va.w << 16)         - __uint_as_float(vb.w << 16)         + 1e-6f; p = fmaf(d, d, p);
        d = __uint_as_float(va.w & 0xffff0000u) - __uint_as_float(vb.w & 0xffff0000u) + 1e-6f; p = fmaf(d, d, p);
    }
    #pragma unroll
    for (int m = 1; m < 16; m <<= 1) p += __shfl_xor(p, m, 64);  // within 16-lane group
    if (lg == 0) sim[node] = sqrtf(p);
}

// ---------------- single-block exact top-512 (sampled threshold) + MLP head ----------------
// Sample 3125 (every 16th), sort 4096 desc, T = 128th largest sample.
// E[count>T] = 2048, sigma ~181 -> P(count<512) ~ 1e-17, P(count>4096) ~ 1e-28.
// count>=512 guarantees top-512 subset of {v > T} (exact).
__global__ __launch_bounds__(1024) void k_topk_mlp(
    const float* __restrict__ sim,
    const float* __restrict__ fc1_w, const float* __restrict__ fc1_b,
    const float* __restrict__ ln1_w, const float* __restrict__ ln1_b,
    const float* __restrict__ fc2_w, const float* __restrict__ fc2_b,
    const float* __restrict__ ln2_w, const float* __restrict__ ln2_b,
    const float* __restrict__ fc3_w, const float* __restrict__ fc3_b,
    float* __restrict__ outp) {
    __shared__ float buf[4096];
    __shared__ float h1p[8][128];
    __shared__ float h1[128];
    __shared__ float h2[64];
    __shared__ float stats[2];
    __shared__ int cnt;
    int t = threadIdx.x;
    // phase 1: sample every 16th sim
    for (int i = t; i < 4096; i += 1024)
        buf[i] = (i < 3125) ? sim[i * 16] : -1.0f;
    __syncthreads();
    // bitonic sort 4096 DESC
    for (int k = 2; k <= 4096; k <<= 1)
        for (int j = k >> 1; j > 0; j >>= 1) {
            for (int i = t; i < 4096; i += 1024) {
                int ixj = i ^ j;
                if (ixj > i) {
                    float a = buf[i], b = buf[ixj];
                    bool dn = ((i & k) == 0);      // desc: front of each k-seq holds larger
                    if ((a < b) == dn) { buf[i] = b; buf[ixj] = a; }
                }
            }
            __syncthreads();
        }
    float T = buf[127];                            // 128th largest sample
    __syncthreads();
    // phase 2: collect candidates > T into buf (LDS atomic counter — one CU, no XCD bounce)
    if (t == 0) cnt = 0;
    __syncthreads();
    for (int i = t; i < N_NODES; i += 1024) {
        float v = sim[i];
        if (v > T) { int p = atomicAdd(&cnt, 1); if (p < 4096) buf[p] = v; }
    }
    __syncthreads();
    int n = cnt < 4096 ? cnt : 4096;
    for (int i = t; i < 4096; i += 1024)
        if (i >= n) buf[i] = -1.0f;
    __syncthreads();
    // phase 3: sort candidates DESC -> buf[0..511] = top-512 sorted
    for (int k = 2; k <= 4096; k <<= 1)
        for (int j = k >> 1; j > 0; j >>= 1) {
            for (int i = t; i < 4096; i += 1024) {
                int ixj = i ^ j;
                if (ixj > i) {
                    float a = buf[i], b = buf[ixj];
                    bool dn = ((i & k) == 0);
                    if ((a < b) == dn) { buf[i] = b; buf[ixj] = a; }
                }
            }
            __syncthreads();
        }
    // phase 4: MLP head. topv[i] = buf[i].
    {
        int o = t & 127, seg = t >> 7;             // 8 segments x 64 terms
        float acc = 0.f;
        for (int i = seg * 64; i < seg * 64 + 64; ++i)
            acc += buf[i] * fc1_w[i * 128 + o];
        h1p[seg][o] = acc;
    }
    __syncthreads();
    if (t < 128) h1[t] = fc1_b[t] + h1p[0][t] + h1p[1][t] + h1p[2][t] + h1p[3][t]
                       + h1p[4][t] + h1p[5][t] + h1p[6][t] + h1p[7][t];
    __syncthreads();
    if (t == 0) {
        float mu = 0.f;
        for (int i = 0; i < 128; ++i) mu += h1[i];
        mu *= (1.f / 128.f);
        float var = 0.f;
        for (int i = 0; i < 128; ++i) { float d = h1[i] - mu; var += d * d; }
        var *= (1.f / 128.f);
        stats[0] = mu; stats[1] = rsqrtf(var + 1e-5f);
    }
    __syncthreads();
    if (t < 128) h1[t] = fmaxf((h1[t] - stats[0]) * stats[1] * ln1_w[t] + ln1_b[t], 0.f);
    __syncthreads();
    if (t < 64) {
        float acc = fc2_b[t];
        for (int i = 0; i < 128; ++i) acc += h1[i] * fc2_w[i * 64 + t];
        h2[t] = acc;
    }
    __syncthreads();
    if (t == 0) {
        float mu = 0.f;
        for (int i = 0; i < 64; ++i) mu += h2[i];
        mu *= (1.f / 64.f);
        float var = 0.f;
        for (int i = 0; i < 64; ++i) { float d = h2[i] - mu; var += d * d; }
        var *= (1.f / 64.f);
        stats[0] = mu; stats[1] = rsqrtf(var + 1e-5f);
    }
    __syncthreads();
    if (t < 64) h2[t] = fmaxf((h2[t] - stats[0]) * stats[1] * ln2_w[t] + ln2_b[t], 0.f);
    __syncthreads();
    if (t == 0) {
        float z = fc3_b[0];
        for (int i = 0; i < 64; ++i) z += h2[i] * fc3_w[i];
        outp[0] = 1.f / (1.f + expf(-z));
    }
}

extern "C" void kernel_launch(void* const* d_in, const int* in_sizes, int n_in,
                              void* d_out, int out_size, void* d_ws, size_t ws_size,
                              hipStream_t stream) {
    const float* x1 = (const float*)d_in[0];
    const float* x2 = (const float*)d_in[1];
    const int* ei1 = (const int*)d_in[2];
    const int* ei2 = (const int*)d_in[3];
    const float* W1 = (const float*)d_in[4];
    const float* as1 = (const float*)d_in[5];
    const float* ad1 = (const float*)d_in[6];
    const float* b1 = (const float*)d_in[7];
    const float* W2 = (const float*)d_in[8];
    const float* as2 = (const float*)d_in[9];
    const float* ad2 = (const float*)d_in[10];
    const float* b2 = (const float*)d_in[11];
    const float* fc1_w = (const float*)d_in[12];
    const float* fc1_b = (const float*)d_in[13];
    const float* ln1_w = (const float*)d_in[14];
    const float* ln1_b = (const float*)d_in[15];
    const float* fc2_w = (const float*)d_in[16];
    const float* fc2_b = (const float*)d_in[17];
    const float* ln2_w = (const float*)d_in[18];
    const float* ln2_b = (const float*)d_in[19];
    const float* fc3_w = (const float*)d_in[20];
    const float* fc3_b = (const float*)d_in[21];
    float* outp = (float*)d_out;

    char* ws = (char*)d_ws;
    size_t off = 0;
    auto alloc = [&](size_t bytes) -> void* {
        void* p = ws + off;
        off = (off + bytes + 255) & ~(size_t)255;
        return p;
    };
    unsigned short* xpA = (unsigned short*)alloc((size_t)N_NODES * 128 * 2);
    unsigned short* xpB = (unsigned short*)alloc((size_t)N_NODES * 128 * 2);
    unsigned short* tmpA = (unsigned short*)alloc((size_t)N_NODES * 128 * 2);
    unsigned short* tmpB = (unsigned short*)alloc((size_t)N_NODES * 128 * 2);
    int* ssrc1  = (int*)alloc((size_t)N_EDGES * 4);
    int* ssrc2  = (int*)alloc((size_t)N_EDGES * 4);
    int* rp1    = (int*)alloc((size_t)(N_NODES + 1) * 4);
    int* rp2    = (int*)alloc((size_t)(N_NODES + 1) * 4);
    float2* alsA = (float2*)alloc((size_t)N_NODES * 8);
    float2* aldA = (float2*)alloc((size_t)N_NODES * 8);
    float2* alsB = (float2*)alloc((size_t)N_NODES * 8);
    float2* aldB = (float2*)alloc((size_t)N_NODES * 8);
    int* part1 = (int*)alloc(64 * 4);
    int* part2 = (int*)alloc(64 * 4);
    int* bo1   = (int*)alloc(64 * 4);
    int* bo2   = (int*)alloc(64 * 4);
    float* sim = (float*)alloc((size_t)N_NODES * 4);
    // ---- zero-initialized region (one memset) ----
    char* zbase = ws + off;
    int* cnt1 = (int*)alloc((size_t)N_NODES * 4);
    int* cnt2 = (int*)alloc((size_t)N_NODES * 4);
    int* cur1 = (int*)alloc((size_t)N_NODES * 4);
    int* cur2 = (int*)alloc((size_t)N_NODES * 4);
    size_t zsize = (size_t)((ws + off) - zbase);
    hipMemsetAsync(zbase, 0, zsize, stream);

    // CSR for both graphs
    k_count2<<<6250, 256, 0, stream>>>(ei1, ei2, cnt1, cnt2);
    k_scan1<<<dim3(49, 2), 1024, 0, stream>>>(cnt1, cnt2, rp1, rp2, part1, part2);
    k_scan2<<<1, 128, 0, stream>>>(part1, part2, bo1, bo2, rp1, rp2);
    k_scan3<<<dim3(49, 2), 1024, 0, stream>>>(rp1, rp2, bo1, bo2);
    k_scatter2<<<6250, 256, 0, stream>>>(ei1, ei2, rp1, rp2, cur1, cur2, ssrc1, ssrc2);

    dim3 ggrid(782, 2, 2);
    // layer 1 (both graphs); agg partitioned: graph A -> XCD 0-3, graph B -> XCD 4-7
    k_gemm_att<0><<<ggrid, 256, 0, stream>>>(x1, x2, W1, as1, ad1, xpA, xpB, alsA, aldA, alsB, aldB);
    k_agg<<<25000, 256, 0, stream>>>(xpA, alsA, aldA, rp1, ssrc1, tmpA,
                                     xpB, alsB, aldB, rp2, ssrc2, tmpB, b1);
    // layer 2 (both graphs, bf16 input); partitioned agg writes rows, then streaming distance
    k_gemm_att<1><<<ggrid, 256, 0, stream>>>(tmpA, tmpB, W2, as2, ad2,
                                             xpA, xpB, alsA, aldA, alsB, aldB);
    k_agg<<<25000, 256, 0, stream>>>(xpA, alsA, aldA, rp1, ssrc1, tmpA,
                                     xpB, alsB, aldB, rp2, ssrc2, tmpB, b2);
    k_dist<<<3125, 256, 0, stream>>>(tmpA, tmpB, sim);

    // exact top-512 (sampled threshold, single block) + MLP head
    k_topk_mlp<<<1, 1024, 0, stream>>>(sim, fc1_w, fc1_b, ln1_w, ln1_b,
                                       fc2_w, fc2_b, ln2_w, ln2_b, fc3_w, fc3_b, outp);
}